// Round 1
// baseline (496.956 us; speedup 1.0000x reference)
//
#include <hip/hip_runtime.h>
#include <cstdint>
#include <cstddef>

typedef unsigned int u32;
typedef unsigned short u16;

#define NB 64
#define DIN 512
#define UNITS 1024
#define TOPICS 20
#define VOCAB 32000
#define NS_OFF ((size_t)NB * TOPICS * VOCAB)

// ---------- bf16 helpers ----------
__device__ __forceinline__ float bf2f(u16 h) {
    union { u32 u; float f; } c; c.u = ((u32)h) << 16; return c.f;
}
__device__ __forceinline__ u16 f2bf(float f) {
    union { float f; u32 u; } c; c.f = f;
    u32 r = c.u + 0x7FFFu + ((c.u >> 16) & 1u);   // RNE
    return (u16)(r >> 16);
}
template<bool F32>
__device__ __forceinline__ float ldv(const void* p, size_t i) {
    if constexpr (F32) return ((const float*)p)[i];
    else return bf2f(((const u16*)p)[i]);
}
__device__ __forceinline__ float ldr(const void* p, size_t i, bool f32) {
    return f32 ? ((const float*)p)[i] : bf2f(((const u16*)p)[i]);
}

// ---------- threefry2x32-20, key (0,42), partitionable counts (0,i) ----------
__device__ __forceinline__ u32 threefry_bits_partitionable(u32 i) {
    const u32 ks0 = 0u, ks1 = 42u, ks2 = 0u ^ 42u ^ 0x1BD11BDAu;
    u32 x0 = 0u + ks0, x1 = i + ks1;
#define TF_R(r) { x0 += x1; x1 = (x1 << r) | (x1 >> (32 - r)); x1 ^= x0; }
    TF_R(13) TF_R(15) TF_R(26) TF_R(6)
    x0 += ks1; x1 += ks2 + 1u;
    TF_R(17) TF_R(29) TF_R(16) TF_R(24)
    x0 += ks2; x1 += ks0 + 2u;
    TF_R(13) TF_R(15) TF_R(26) TF_R(6)
    x0 += ks0; x1 += ks1 + 3u;
    TF_R(17) TF_R(29) TF_R(16) TF_R(24)
    x0 += ks1; x1 += ks2 + 4u;
    TF_R(13) TF_R(15) TF_R(26) TF_R(6)
    x0 += ks2; x1 += ks0 + 5u;
#undef TF_R
    return x0 ^ x1;
}

// ---------- init: self-detect dtype, eb = exp(beta), zero lsum, publish flag ----------
__global__ __launch_bounds__(256)
void k_init(const void* __restrict__ beta, int* __restrict__ flag,
            float* __restrict__ lsum, float* __restrict__ eb) {
    int tid = threadIdx.x, lane = tid & 63, w = tid >> 6;
    __shared__ int cnt_s[4];
    int cnt = 0;
    const u32* braw = (const u32*)beta;
    for (int i = tid; i < 1024; i += 256) {
        u32 x = braw[i];
        u32 e = (x >> 7) & 0xFFu;
        cnt += (e >= 110u && e <= 132u) ? 1 : 0;
    }
    for (int off = 32; off; off >>= 1) cnt += __shfl_down(cnt, off, 64);
    if (lane == 0) cnt_s[w] = cnt;
    __syncthreads();
    int total = cnt_s[0] + cnt_s[1] + cnt_s[2] + cnt_s[3];
    bool f32 = total < 512;

    size_t base = (size_t)blockIdx.x * 2000;
    for (int i = tid; i < 2000; i += 256)
        eb[base + i] = __expf(ldr(beta, base + i, f32));

    if (blockIdx.x == 0) {
        for (int i = tid; i < NB * TOPICS; i += 256) lsum[i] = 0.f;
        if (tid == 0) flag[0] = f32 ? 1 : 0;
    }
}

// ---------- A: next_state = x@Wxh + h@Whh ----------
template<bool F32>
__device__ void state_body(const void* xin, const void* h0, const void* Wxh,
                           const void* Whh, float* ns_f32, void* dout) {
    __shared__ float lx[DIN + UNITS];
    int b = blockIdx.x >> 2;
    int u = ((blockIdx.x & 3) << 8) | threadIdx.x;
    for (int i = threadIdx.x; i < DIN; i += 256)
        lx[i] = ldv<F32>(xin, (size_t)b * DIN + i);
    for (int i = threadIdx.x; i < UNITS; i += 256)
        lx[DIN + i] = ldv<F32>(h0, (size_t)b * UNITS + i);
    __syncthreads();
    float acc = 0.f;
#pragma unroll 8
    for (int k = 0; k < DIN; ++k)   acc += lx[k]       * ldv<F32>(Wxh, (size_t)k * UNITS + u);
#pragma unroll 8
    for (int k = 0; k < UNITS; ++k) acc += lx[DIN + k] * ldv<F32>(Whh, (size_t)k * UNITS + u);
    int idx = b * UNITS + u;
    ns_f32[idx] = acc;
    if constexpr (F32) ((float*)dout)[NS_OFF + idx] = acc;
    else               ((u16*)dout)[NS_OFF + idx]   = f2bf(acc);
}
__global__ __launch_bounds__(256)
void k_state(const int* __restrict__ flag, const void* xin, const void* h0,
             const void* Wxh, const void* Whh,
             float* __restrict__ ns_f32, void* dout) {
    if (*flag) state_body<true>(xin, h0, Wxh, Whh, ns_f32, dout);
    else       state_body<false>(xin, h0, Wxh, Whh, ns_f32, dout);
}

// ---------- B: coeff_b = 1 - bernoulli_sample ----------
template<bool F32>
__device__ void bern_body(const float* ns, const void* bk, float* coeff) {
    int b = blockIdx.x, lane = threadIdx.x;
    float s = 0.f;
#pragma unroll
    for (int i = 0; i < UNITS / 64; ++i) {
        int k = lane + (i << 6);
        s += ns[b * UNITS + k] * ldv<F32>(bk, k);
    }
    for (int off = 32; off; off >>= 1) s += __shfl_down(s, off, 64);
    if (lane == 0) {
        float sp = log1pf(expf(s));              // softplus
        float p  = 1.f / (1.f + expf(-sp));      // sigmoid
        u32 bits = threefry_bits_partitionable((u32)b);
        union { u32 u; float f; } c; c.u = (bits >> 9) | 0x3f800000u;
        float uni = c.f - 1.0f;
        coeff[b] = (uni < p) ? 0.f : 1.f;        // (1 - sample)
    }
}
__global__ __launch_bounds__(64)
void k_bern(const int* __restrict__ flag, const float* __restrict__ ns,
            const void* bk, float* __restrict__ coeff) {
    if (*flag) bern_body<true>(ns, bk, coeff);
    else       bern_body<false>(ns, bk, coeff);
}

// ---------- C: esv[b][v] = exp( ns[b][:] @ Wv[:,v] )  (re-tiled GEMM) ----------
// grid 250 blocks (v-tile 128), 128 threads (2 waves), thread tile 8b x 8v.
// One block covers ALL 64 b rows. K staged in 16 tiles of 64.
//   As: transposed [k][b], row stride 68 floats -> compute reads are
//       4 addresses x 16-lane broadcast, banks {0,8,16,24}: conflict-free.
//   Bs: [k][16 v-chunks of 8 floats, chunk stride 12 floats (48B, keeps
//       ds_read_b128 16B-aligned)] -> 16 read addresses on 8 bank-starts
//       = 2-way = free (vs 4-way for dense layout).
// LDS bytes/FMA: 1.0 (was 2.5) -> VALU-bound (~55us floor), not LDS-bound.
// Next tile is prefetched into registers before compute (hides HBM stage).
#define SV_KT 64
#define SV_AP 68            // As row stride in floats
#define SV_BP 192           // Bs row stride in floats (16 chunks * 12)
template<bool F32>
__device__ void sv_body(const float* __restrict__ ns, const void* __restrict__ Wv,
                        float* __restrict__ esv) {
    __shared__ float As[SV_KT * SV_AP];   // [k][b]
    __shared__ float Bs[SV_KT * SV_BP];   // [k][chunk*12 + j]
    const int tid = threadIdx.x;
    const int tb = tid >> 4;              // 0..7  -> rows b = tb*8 .. tb*8+7
    const int tv = tid & 15;              // 0..15 -> cols v = tv*8 .. tv*8+7
    const int v0 = blockIdx.x * 128;

    // A staging map: b = tid>>1, k-half = (tid&1)*32 -> 8 float4 loads
    const int sa_b = tid >> 1;
    const int sa_k = (tid & 1) * 32;

    float4  aR[8];
    float4  bR[16];
    ushort4 bRh[16];

    float acc[8][8];
#pragma unroll
    for (int r = 0; r < 8; ++r)
#pragma unroll
        for (int c = 0; c < 8; ++c) acc[r][c] = 0.f;

    // ---- prologue: load tile 0 into registers ----
#pragma unroll
    for (int j = 0; j < 8; ++j)
        aR[j] = *(const float4*)&ns[(size_t)sa_b * UNITS + sa_k + j * 4];
#pragma unroll
    for (int i = 0; i < 16; ++i) {
        int e = tid + i * 128, row = e >> 5, c4 = e & 31;
        if constexpr (F32)
            bR[i] = *(const float4*)((const float*)Wv + (size_t)row * VOCAB + v0 + c4 * 4);
        else
            bRh[i] = *(const ushort4*)((const u16*)Wv + (size_t)row * VOCAB + v0 + c4 * 4);
    }

    for (int t = 0; t < 16; ++t) {
        // ---- write staged registers to LDS (compiler inserts vmcnt wait) ----
#pragma unroll
        for (int j = 0; j < 8; ++j) {
            int kl = sa_k + j * 4;
            As[(kl + 0) * SV_AP + sa_b] = aR[j].x;
            As[(kl + 1) * SV_AP + sa_b] = aR[j].y;
            As[(kl + 2) * SV_AP + sa_b] = aR[j].z;
            As[(kl + 3) * SV_AP + sa_b] = aR[j].w;
        }
#pragma unroll
        for (int i = 0; i < 16; ++i) {
            int e = tid + i * 128, row = e >> 5, c4 = e & 31;
            float4 w;
            if constexpr (F32) w = bR[i];
            else { w.x = bf2f(bRh[i].x); w.y = bf2f(bRh[i].y);
                   w.z = bf2f(bRh[i].z); w.w = bf2f(bRh[i].w); }
            *(float4*)&Bs[row * SV_BP + (c4 >> 1) * 12 + (c4 & 1) * 4] = w;
        }
        __syncthreads();

        // ---- issue prefetch of tile t+1 (overlaps with compute below) ----
        if (t < 15) {
            int k0n = (t + 1) * SV_KT;
#pragma unroll
            for (int j = 0; j < 8; ++j)
                aR[j] = *(const float4*)&ns[(size_t)sa_b * UNITS + k0n + sa_k + j * 4];
#pragma unroll
            for (int i = 0; i < 16; ++i) {
                int e = tid + i * 128, row = e >> 5, c4 = e & 31;
                if constexpr (F32)
                    bR[i] = *(const float4*)((const float*)Wv + (size_t)(k0n + row) * VOCAB + v0 + c4 * 4);
                else
                    bRh[i] = *(const ushort4*)((const u16*)Wv + (size_t)(k0n + row) * VOCAB + v0 + c4 * 4);
            }
        }

        // ---- compute: 64 k-steps, 64 FMA each, 4 ds_read_b128 per step ----
#pragma unroll 8
        for (int kk = 0; kk < SV_KT; ++kk) {
            float4 a0 = *(const float4*)&As[kk * SV_AP + tb * 8];
            float4 a1 = *(const float4*)&As[kk * SV_AP + tb * 8 + 4];
            float4 b0 = *(const float4*)&Bs[kk * SV_BP + tv * 12];
            float4 b1 = *(const float4*)&Bs[kk * SV_BP + tv * 12 + 4];
            float av[8] = {a0.x, a0.y, a0.z, a0.w, a1.x, a1.y, a1.z, a1.w};
            float bv[8] = {b0.x, b0.y, b0.z, b0.w, b1.x, b1.y, b1.z, b1.w};
#pragma unroll
            for (int r = 0; r < 8; ++r)
#pragma unroll
                for (int c = 0; c < 8; ++c)
                    acc[r][c] = fmaf(av[r], bv[c], acc[r][c]);
        }
        __syncthreads();
    }

    // ---- epilogue: exp + store ----
#pragma unroll
    for (int r = 0; r < 8; ++r) {
        float4 e0, e1;
        e0.x = __expf(acc[r][0]); e0.y = __expf(acc[r][1]);
        e0.z = __expf(acc[r][2]); e0.w = __expf(acc[r][3]);
        e1.x = __expf(acc[r][4]); e1.y = __expf(acc[r][5]);
        e1.z = __expf(acc[r][6]); e1.w = __expf(acc[r][7]);
        float* dst = esv + (size_t)(tb * 8 + r) * VOCAB + v0 + tv * 8;
        *(float4*)dst = e0;
        *(float4*)(dst + 4) = e1;
    }
}
__global__ __launch_bounds__(128)
void k_sv(const int* __restrict__ flag, const float* __restrict__ ns,
          const void* Wv, float* __restrict__ esv) {
    if (*flag) sv_body<true>(ns, Wv, esv);
    else       sv_body<false>(ns, Wv, esv);
}

// ---------- D1: lsum[b][t] = sum_v esv[b][v] * (c ? eb[t][v] : 1) ----------
__global__ __launch_bounds__(256)
void k_sum(const float* __restrict__ esv, const float* __restrict__ eb,
           const float* __restrict__ coeff, float* __restrict__ lsum) {
    int b = blockIdx.y, tid = threadIdx.x;
    float c = coeff[b];
    const float4* e4 = (const float4*)(esv + (size_t)b * VOCAB);
    int i0 = blockIdx.x * 256 + tid;
    __shared__ float red[4][TOPICS];
    int lane = tid & 63, w = tid >> 6;

    if (c != 0.f) {
        float acc[TOPICS];
#pragma unroll
        for (int t = 0; t < TOPICS; ++t) acc[t] = 0.f;
        for (int i = i0; i < VOCAB / 4; i += 4096) {
            float4 e = e4[i];
#pragma unroll
            for (int t = 0; t < TOPICS; ++t) {
                float4 g = *(const float4*)(eb + (size_t)t * VOCAB + i * 4);
                acc[t] += e.x * g.x + e.y * g.y + e.z * g.z + e.w * g.w;
            }
        }
#pragma unroll
        for (int t = 0; t < TOPICS; ++t) {
            float v = acc[t];
            for (int off = 32; off; off >>= 1) v += __shfl_down(v, off, 64);
            if (lane == 0) red[w][t] = v;
        }
        __syncthreads();
        if (tid < TOPICS) {
            float s = red[0][tid] + red[1][tid] + red[2][tid] + red[3][tid];
            atomicAdd(&lsum[b * TOPICS + tid], s);
        }
    } else {
        float a = 0.f;
        for (int i = i0; i < VOCAB / 4; i += 4096) {
            float4 e = e4[i];
            a += e.x + e.y + e.z + e.w;
        }
        for (int off = 32; off; off >>= 1) a += __shfl_down(a, off, 64);
        if (lane == 0) red[w][0] = a;
        __syncthreads();
        if (tid < TOPICS) {
            float s = red[0][0] + red[1][0] + red[2][0] + red[3][0];
            atomicAdd(&lsum[b * TOPICS + tid], s);
        }
    }
}

// ---------- D2: out[b][t][v] = esv[b][v] * (c ? eb[t][v] : 1) / lsum[b][t] ----------
template<bool F32>
__device__ void write_body(const float* esv, const float* eb, const float* coeff,
                           const float* lsum, void* dout) {
    int b = blockIdx.y, tid = threadIdx.x;
    int v0 = blockIdx.x * 2048 + tid * 8;
    if (v0 >= VOCAB) return;
    float c = coeff[b];
    const float* er = esv + (size_t)b * VOCAB + v0;
    float4 e0 = *(const float4*)er;
    float4 e1 = *(const float4*)(er + 4);
#pragma unroll 4
    for (int t = 0; t < TOPICS; ++t) {
        float inv = 1.0f / lsum[b * TOPICS + t];
        float o0, o1, o2, o3, o4, o5, o6, o7;
        if (c != 0.f) {
            const float* gr = eb + (size_t)t * VOCAB + v0;
            float4 g0 = *(const float4*)gr;
            float4 g1 = *(const float4*)(gr + 4);
            o0 = e0.x * g0.x * inv; o1 = e0.y * g0.y * inv;
            o2 = e0.z * g0.z * inv; o3 = e0.w * g0.w * inv;
            o4 = e1.x * g1.x * inv; o5 = e1.y * g1.y * inv;
            o6 = e1.z * g1.z * inv; o7 = e1.w * g1.w * inv;
        } else {
            o0 = e0.x * inv; o1 = e0.y * inv; o2 = e0.z * inv; o3 = e0.w * inv;
            o4 = e1.x * inv; o5 = e1.y * inv; o6 = e1.z * inv; o7 = e1.w * inv;
        }
        size_t off = (size_t)b * TOPICS * VOCAB + (size_t)t * VOCAB + v0;
        if constexpr (F32) {
            float4 s0 = {o0, o1, o2, o3}, s1 = {o4, o5, o6, o7};
            *(float4*)((float*)dout + off) = s0;
            *(float4*)((float*)dout + off + 4) = s1;
        } else {
            uint4 st;
            st.x = (u32)f2bf(o0) | ((u32)f2bf(o1) << 16);
            st.y = (u32)f2bf(o2) | ((u32)f2bf(o3) << 16);
            st.z = (u32)f2bf(o4) | ((u32)f2bf(o5) << 16);
            st.w = (u32)f2bf(o6) | ((u32)f2bf(o7) << 16);
            *(uint4*)((u16*)dout + off) = st;
        }
    }
}
__global__ __launch_bounds__(256)
void k_write(const int* __restrict__ flag, const float* __restrict__ esv,
             const float* __restrict__ eb, const float* __restrict__ coeff,
             const float* __restrict__ lsum, void* dout) {
    if (*flag) write_body<true>(esv, eb, coeff, lsum, dout);
    else       write_body<false>(esv, eb, coeff, lsum, dout);
}

extern "C" void kernel_launch(void* const* d_in, const int* in_sizes, int n_in,
                              void* d_out, int out_size, void* d_ws, size_t ws_size,
                              hipStream_t stream) {
    const void* xin  = d_in[0];
    const void* h0   = d_in[1];
    const void* Wxh  = d_in[2];
    const void* Whh  = d_in[3];
    const void* bk   = d_in[4];
    const void* Wv   = d_in[5];
    const void* beta = d_in[6];

    char* ws = (char*)d_ws;
    int*   flag   = (int*)  (ws + 0);
    float* coeff  = (float*)(ws + 256);
    float* lsum   = (float*)(ws + 1024);      // 1280 f -> ends 6144
    float* ns_f32 = (float*)(ws + 8192);      // 256 KiB -> ends 270336
    float* eb     = (float*)(ws + 270336);    // 2.56 MB -> ends 2830336
    float* esv    = (float*)(ws + 2830336);   // 8.192 MB -> ends 11022336

    k_init <<<320, 256, 0, stream>>>(beta, flag, lsum, eb);
    k_state<<<256, 256, 0, stream>>>(flag, xin, h0, Wxh, Whh, ns_f32, d_out);
    k_bern <<<64, 64, 0, stream>>>(flag, ns_f32, bk, coeff);
    k_sv   <<<250, 128, 0, stream>>>(flag, ns_f32, Wv, esv);
    k_sum  <<<dim3(16, 64), 256, 0, stream>>>(esv, eb, coeff, lsum);
    k_write<<<dim3(16, 64), 256, 0, stream>>>(flag, esv, eb, coeff, lsum, d_out);
}

// Round 2
// 482.592 us; speedup vs baseline: 1.0298x; 1.0298x over previous
//
#include <hip/hip_runtime.h>
#include <cstdint>
#include <cstddef>

typedef unsigned int u32;
typedef unsigned short u16;

#define NB 64
#define DIN 512
#define UNITS 1024
#define TOPICS 20
#define VOCAB 32000
#define NS_OFF ((size_t)NB * TOPICS * VOCAB)

typedef __attribute__((ext_vector_type(8))) short s16x8;
typedef __attribute__((ext_vector_type(4))) float f32x4;

// ---------- bf16 helpers ----------
__device__ __forceinline__ float bf2f(u16 h) {
    union { u32 u; float f; } c; c.u = ((u32)h) << 16; return c.f;
}
__device__ __forceinline__ u16 f2bf(float f) {
    union { float f; u32 u; } c; c.f = f;
    u32 r = c.u + 0x7FFFu + ((c.u >> 16) & 1u);   // RNE
    return (u16)(r >> 16);
}
template<bool F32>
__device__ __forceinline__ float ldv(const void* p, size_t i) {
    if constexpr (F32) return ((const float*)p)[i];
    else return bf2f(((const u16*)p)[i]);
}
__device__ __forceinline__ float ldr(const void* p, size_t i, bool f32) {
    return f32 ? ((const float*)p)[i] : bf2f(((const u16*)p)[i]);
}

// ---------- threefry2x32-20, key (0,42), partitionable counts (0,i) ----------
__device__ __forceinline__ u32 threefry_bits_partitionable(u32 i) {
    const u32 ks0 = 0u, ks1 = 42u, ks2 = 0u ^ 42u ^ 0x1BD11BDAu;
    u32 x0 = 0u + ks0, x1 = i + ks1;
#define TF_R(r) { x0 += x1; x1 = (x1 << r) | (x1 >> (32 - r)); x1 ^= x0; }
    TF_R(13) TF_R(15) TF_R(26) TF_R(6)
    x0 += ks1; x1 += ks2 + 1u;
    TF_R(17) TF_R(29) TF_R(16) TF_R(24)
    x0 += ks2; x1 += ks0 + 2u;
    TF_R(13) TF_R(15) TF_R(26) TF_R(6)
    x0 += ks0; x1 += ks1 + 3u;
    TF_R(17) TF_R(29) TF_R(16) TF_R(24)
    x0 += ks1; x1 += ks2 + 4u;
    TF_R(13) TF_R(15) TF_R(26) TF_R(6)
    x0 += ks2; x1 += ks0 + 5u;
#undef TF_R
    return x0 ^ x1;
}

// ---------- init: self-detect dtype, eb = exp(beta), zero lsum, publish flag ----------
__global__ __launch_bounds__(256)
void k_init(const void* __restrict__ beta, int* __restrict__ flag,
            float* __restrict__ lsum, float* __restrict__ eb) {
    int tid = threadIdx.x, lane = tid & 63, w = tid >> 6;
    __shared__ int cnt_s[4];
    int cnt = 0;
    const u32* braw = (const u32*)beta;
    for (int i = tid; i < 1024; i += 256) {
        u32 x = braw[i];
        u32 e = (x >> 7) & 0xFFu;
        cnt += (e >= 110u && e <= 132u) ? 1 : 0;
    }
    for (int off = 32; off; off >>= 1) cnt += __shfl_down(cnt, off, 64);
    if (lane == 0) cnt_s[w] = cnt;
    __syncthreads();
    int total = cnt_s[0] + cnt_s[1] + cnt_s[2] + cnt_s[3];
    bool f32 = total < 512;

    size_t base = (size_t)blockIdx.x * 2000;
    for (int i = tid; i < 2000; i += 256)
        eb[base + i] = __expf(ldr(beta, base + i, f32));

    if (blockIdx.x == 0) {
        for (int i = tid; i < NB * TOPICS; i += 256) lsum[i] = 0.f;
        if (tid == 0) flag[0] = f32 ? 1 : 0;
    }
}

// ---------- A: next_state = x@Wxh + h@Whh ----------
template<bool F32>
__device__ void state_body(const void* xin, const void* h0, const void* Wxh,
                           const void* Whh, float* ns_f32, void* dout) {
    __shared__ float lx[DIN + UNITS];
    int b = blockIdx.x >> 2;
    int u = ((blockIdx.x & 3) << 8) | threadIdx.x;
    for (int i = threadIdx.x; i < DIN; i += 256)
        lx[i] = ldv<F32>(xin, (size_t)b * DIN + i);
    for (int i = threadIdx.x; i < UNITS; i += 256)
        lx[DIN + i] = ldv<F32>(h0, (size_t)b * UNITS + i);
    __syncthreads();
    float acc = 0.f;
#pragma unroll 8
    for (int k = 0; k < DIN; ++k)   acc += lx[k]       * ldv<F32>(Wxh, (size_t)k * UNITS + u);
#pragma unroll 8
    for (int k = 0; k < UNITS; ++k) acc += lx[DIN + k] * ldv<F32>(Whh, (size_t)k * UNITS + u);
    int idx = b * UNITS + u;
    ns_f32[idx] = acc;
    if constexpr (F32) ((float*)dout)[NS_OFF + idx] = acc;
    else               ((u16*)dout)[NS_OFF + idx]   = f2bf(acc);
}
__global__ __launch_bounds__(256)
void k_state(const int* __restrict__ flag, const void* xin, const void* h0,
             const void* Wxh, const void* Whh,
             float* __restrict__ ns_f32, void* dout) {
    if (*flag) state_body<true>(xin, h0, Wxh, Whh, ns_f32, dout);
    else       state_body<false>(xin, h0, Wxh, Whh, ns_f32, dout);
}

// ---------- B: coeff_b = 1 - bernoulli_sample ----------
template<bool F32>
__device__ void bern_body(const float* ns, const void* bk, float* coeff) {
    int b = blockIdx.x, lane = threadIdx.x;
    float s = 0.f;
#pragma unroll
    for (int i = 0; i < UNITS / 64; ++i) {
        int k = lane + (i << 6);
        s += ns[b * UNITS + k] * ldv<F32>(bk, k);
    }
    for (int off = 32; off; off >>= 1) s += __shfl_down(s, off, 64);
    if (lane == 0) {
        float sp = log1pf(expf(s));              // softplus
        float p  = 1.f / (1.f + expf(-sp));      // sigmoid
        u32 bits = threefry_bits_partitionable((u32)b);
        union { u32 u; float f; } c; c.u = (bits >> 9) | 0x3f800000u;
        float uni = c.f - 1.0f;
        coeff[b] = (uni < p) ? 0.f : 1.f;        // (1 - sample)
    }
}
__global__ __launch_bounds__(64)
void k_bern(const int* __restrict__ flag, const float* __restrict__ ns,
            const void* bk, float* __restrict__ coeff) {
    if (*flag) bern_body<true>(ns, bk, coeff);
    else       bern_body<false>(ns, bk, coeff);
}

// ============================================================================
// C: esv[b][v] = exp( ns[b][:] @ Wv[:,v] )
//   bf16 path: MFMA 16x16x32_bf16. grid 500 x 256thr (4 waves).
//     block v-tile 64; wave w owns cols w*16..w*16+15, all 64 b rows.
//     A (= bf16 next_state already in dout) staged per K-tile(64) into
//     16KB double-buffered LDS, XOR-swizzled -> conflict-free ds_read_b128.
//     B frags loaded global->reg (8 x u16, k-strided; block's waves cover
//     128B of each k-row so L2 merges lines), double-buffered in named regs.
//   f32 path: session-verified VALU tile (2b x 8v, PAD=68). __shared__ is
//     hoisted to the __global__ fn so only ONE copy allocates (the round-1
//     regression was BOTH template instantiations allocating -> 130KB LDS,
//     2 waves/CU, 5% occupancy).
// ============================================================================
#define PAD 68
#define SV_SMEM_BYTES (2 * 64 * PAD * 4)   // 34816 B (f32 path); mfma needs 16384

__device__ __forceinline__ void sv_mfma_body(const short* __restrict__ ns16,
                                             const short* __restrict__ Wv,
                                             float* __restrict__ esv,
                                             char* smem_raw) {
    short* As = (short*)smem_raw;          // [2][64][64] bf16, 16B-chunk swizzled
    const int tid  = threadIdx.x;
    const int lane = tid & 63;
    const int wn   = tid >> 6;             // wave 0..3
    const int v0   = blockIdx.x * 64;
    const int col  = v0 + wn * 16 + (lane & 15);
    const int krow = (lane >> 4) * 8;      // frag k-base within 32-chunk

    const short* Bcol = Wv + col;

    f32x4 acc[4];
#pragma unroll
    for (int m = 0; m < 4; ++m) acc[m] = (f32x4){0.f, 0.f, 0.f, 0.f};

    short bA[16], bB[16];                  // named double buffers [kf*8+e]

    auto loadB = [&](short* buf, int t) {
#pragma unroll
        for (int kf = 0; kf < 2; ++kf)
#pragma unroll
            for (int e = 0; e < 8; ++e)
                buf[kf * 8 + e] = Bcol[(size_t)(t * 64 + kf * 32 + krow + e) * VOCAB];
    };
    auto stageA = [&](int dbase, int t) {
#pragma unroll
        for (int r = 0; r < 2; ++r) {
            int e = tid + r * 256;         // 512 chunks of 8 bf16
            int row = e >> 3, c = e & 7;
            s16x8 v = *(const s16x8*)&ns16[(size_t)row * UNITS + t * 64 + c * 8];
            *(s16x8*)&As[dbase + row * 64 + ((c * 8) ^ ((row & 7) << 3))] = v;
        }
    };
    auto compute = [&](int dbase, const short* buf) {
        s16x8 aF[4][2];
#pragma unroll
        for (int mf = 0; mf < 4; ++mf)
#pragma unroll
            for (int kf = 0; kf < 2; ++kf) {
                int row = mf * 16 + (lane & 15);
                int co  = (kf * 32 + krow) ^ ((row & 7) << 3);
                aF[mf][kf] = *(const s16x8*)&As[dbase + row * 64 + co];
            }
#pragma unroll
        for (int kf = 0; kf < 2; ++kf) {
            s16x8 bF;
#pragma unroll
            for (int e = 0; e < 8; ++e) bF[e] = buf[kf * 8 + e];
#pragma unroll
            for (int mf = 0; mf < 4; ++mf)
                acc[mf] = __builtin_amdgcn_mfma_f32_16x16x32_bf16(
                              aF[mf][kf], bF, acc[mf], 0, 0, 0);
        }
    };

    loadB(bA, 0);                          // prologue prefetch
    for (int t = 0; t < 16; t += 2) {
        stageA(0, t);
        __syncthreads();
        loadB(bB, t + 1);
        compute(0, bA);
        stageA(64 * 64, t + 1);
        __syncthreads();
        if (t + 2 < 16) loadB(bA, t + 2);
        compute(64 * 64, bB);
    }

    // C/D layout: row=(lane>>4)*4+reg, col=lane&15  [m89-verified]
#pragma unroll
    for (int mf = 0; mf < 4; ++mf)
#pragma unroll
        for (int r = 0; r < 4; ++r) {
            int b = mf * 16 + (lane >> 4) * 4 + r;
            esv[(size_t)b * VOCAB + col] = __expf(acc[mf][r]);
        }
}

__device__ void sv_f32_body(const float* __restrict__ ns, const float* __restrict__ Wv,
                            float* __restrict__ esv, float* As, float* Bs) {
    int tid = threadIdx.x;
    int vt = tid & 7;           // 8 v-threads x 8 v = 64 v
    int bg = tid >> 3;          // 32 groups x 2 b = 64 b
    int v0 = blockIdx.x * 64;
    float acc[2][8];
#pragma unroll
    for (int r = 0; r < 2; ++r)
#pragma unroll
        for (int j = 0; j < 8; ++j) acc[r][j] = 0.f;

    for (int k0 = 0; k0 < UNITS; k0 += 64) {
        __syncthreads();
        for (int e = tid; e < 1024; e += 256) {      // stage A: ns[64b][64k]
            int row = e >> 4, c4 = e & 15;
            *(float4*)&As[row * PAD + c4 * 4] =
                *(const float4*)&ns[row * UNITS + k0 + c4 * 4];
        }
        for (int e = tid; e < 1024; e += 256) {      // stage B: Wv[64k][64v]
            int row = e >> 4, c4 = e & 15;
            *(float4*)&Bs[row * PAD + c4 * 4] =
                *(const float4*)(Wv + (size_t)(k0 + row) * VOCAB + v0 + c4 * 4);
        }
        __syncthreads();
#pragma unroll 4
        for (int u = 0; u < 64; u += 4) {
            float4 a0 = *(float4*)&As[(bg * 2 + 0) * PAD + u];
            float4 a1 = *(float4*)&As[(bg * 2 + 1) * PAD + u];
            float aa0[4] = {a0.x, a0.y, a0.z, a0.w};
            float aa1[4] = {a1.x, a1.y, a1.z, a1.w};
#pragma unroll
            for (int uu = 0; uu < 4; ++uu) {
                float4 b0 = *(float4*)&Bs[(u + uu) * PAD + vt * 8];
                float4 b1 = *(float4*)&Bs[(u + uu) * PAD + vt * 8 + 4];
                float bb[8] = {b0.x, b0.y, b0.z, b0.w, b1.x, b1.y, b1.z, b1.w};
#pragma unroll
                for (int j = 0; j < 8; ++j) {
                    acc[0][j] = fmaf(aa0[uu], bb[j], acc[0][j]);
                    acc[1][j] = fmaf(aa1[uu], bb[j], acc[1][j]);
                }
            }
        }
    }
#pragma unroll
    for (int r = 0; r < 2; ++r) {
        float4 e0, e1;
        e0.x = __expf(acc[r][0]); e0.y = __expf(acc[r][1]);
        e0.z = __expf(acc[r][2]); e0.w = __expf(acc[r][3]);
        e1.x = __expf(acc[r][4]); e1.y = __expf(acc[r][5]);
        e1.z = __expf(acc[r][6]); e1.w = __expf(acc[r][7]);
        float* dst = esv + (size_t)(bg * 2 + r) * VOCAB + v0 + vt * 8;
        *(float4*)dst = e0;
        *(float4*)(dst + 4) = e1;
    }
}

__global__ __launch_bounds__(256)
void k_sv(const int* __restrict__ flag, const float* __restrict__ ns,
          const void* Wv, const void* dout, float* __restrict__ esv) {
    __shared__ __align__(16) char smem[SV_SMEM_BYTES];
    if (*flag) {
        float* As = (float*)smem;
        sv_f32_body(ns, (const float*)Wv, esv, As, As + 64 * PAD);
    } else {
        sv_mfma_body((const short*)dout + NS_OFF, (const short*)Wv, esv, smem);
    }
}

// ---------- D1: lsum[b][t] = sum_v esv[b][v] * (c ? eb[t][v] : 1) ----------
__global__ __launch_bounds__(256)
void k_sum(const float* __restrict__ esv, const float* __restrict__ eb,
           const float* __restrict__ coeff, float* __restrict__ lsum) {
    int b = blockIdx.y, tid = threadIdx.x;
    float c = coeff[b];
    const float4* e4 = (const float4*)(esv + (size_t)b * VOCAB);
    int i0 = blockIdx.x * 256 + tid;
    __shared__ float red[4][TOPICS];
    int lane = tid & 63, w = tid >> 6;

    if (c != 0.f) {
        float acc[TOPICS];
#pragma unroll
        for (int t = 0; t < TOPICS; ++t) acc[t] = 0.f;
        for (int i = i0; i < VOCAB / 4; i += 4096) {
            float4 e = e4[i];
#pragma unroll
            for (int t = 0; t < TOPICS; ++t) {
                float4 g = *(const float4*)(eb + (size_t)t * VOCAB + i * 4);
                acc[t] += e.x * g.x + e.y * g.y + e.z * g.z + e.w * g.w;
            }
        }
#pragma unroll
        for (int t = 0; t < TOPICS; ++t) {
            float v = acc[t];
            for (int off = 32; off; off >>= 1) v += __shfl_down(v, off, 64);
            if (lane == 0) red[w][t] = v;
        }
        __syncthreads();
        if (tid < TOPICS) {
            float s = red[0][tid] + red[1][tid] + red[2][tid] + red[3][tid];
            atomicAdd(&lsum[b * TOPICS + tid], s);
        }
    } else {
        float a = 0.f;
        for (int i = i0; i < VOCAB / 4; i += 4096) {
            float4 e = e4[i];
            a += e.x + e.y + e.z + e.w;
        }
        for (int off = 32; off; off >>= 1) a += __shfl_down(a, off, 64);
        if (lane == 0) red[w][0] = a;
        __syncthreads();
        if (tid < TOPICS) {
            float s = red[0][0] + red[1][0] + red[2][0] + red[3][0];
            atomicAdd(&lsum[b * TOPICS + tid], s);
        }
    }
}

// ---------- D2: out[b][t][v] = esv[b][v] * (c ? eb[t][v] : 1) / lsum[b][t] ----------
template<bool F32>
__device__ void write_body(const float* esv, const float* eb, const float* coeff,
                           const float* lsum, void* dout) {
    int b = blockIdx.y, tid = threadIdx.x;
    int v0 = blockIdx.x * 2048 + tid * 8;
    if (v0 >= VOCAB) return;
    float c = coeff[b];
    const float* er = esv + (size_t)b * VOCAB + v0;
    float4 e0 = *(const float4*)er;
    float4 e1 = *(const float4*)(er + 4);
#pragma unroll 4
    for (int t = 0; t < TOPICS; ++t) {
        float inv = 1.0f / lsum[b * TOPICS + t];
        float o0, o1, o2, o3, o4, o5, o6, o7;
        if (c != 0.f) {
            const float* gr = eb + (size_t)t * VOCAB + v0;
            float4 g0 = *(const float4*)gr;
            float4 g1 = *(const float4*)(gr + 4);
            o0 = e0.x * g0.x * inv; o1 = e0.y * g0.y * inv;
            o2 = e0.z * g0.z * inv; o3 = e0.w * g0.w * inv;
            o4 = e1.x * g1.x * inv; o5 = e1.y * g1.y * inv;
            o6 = e1.z * g1.z * inv; o7 = e1.w * g1.w * inv;
        } else {
            o0 = e0.x * inv; o1 = e0.y * inv; o2 = e0.z * inv; o3 = e0.w * inv;
            o4 = e1.x * inv; o5 = e1.y * inv; o6 = e1.z * inv; o7 = e1.w * inv;
        }
        size_t off = (size_t)b * TOPICS * VOCAB + (size_t)t * VOCAB + v0;
        if constexpr (F32) {
            float4 s0 = {o0, o1, o2, o3}, s1 = {o4, o5, o6, o7};
            *(float4*)((float*)dout + off) = s0;
            *(float4*)((float*)dout + off + 4) = s1;
        } else {
            uint4 st;
            st.x = (u32)f2bf(o0) | ((u32)f2bf(o1) << 16);
            st.y = (u32)f2bf(o2) | ((u32)f2bf(o3) << 16);
            st.z = (u32)f2bf(o4) | ((u32)f2bf(o5) << 16);
            st.w = (u32)f2bf(o6) | ((u32)f2bf(o7) << 16);
            *(uint4*)((u16*)dout + off) = st;
        }
    }
}
__global__ __launch_bounds__(256)
void k_write(const int* __restrict__ flag, const float* __restrict__ esv,
             const float* __restrict__ eb, const float* __restrict__ coeff,
             const float* __restrict__ lsum, void* dout) {
    if (*flag) write_body<true>(esv, eb, coeff, lsum, dout);
    else       write_body<false>(esv, eb, coeff, lsum, dout);
}

extern "C" void kernel_launch(void* const* d_in, const int* in_sizes, int n_in,
                              void* d_out, int out_size, void* d_ws, size_t ws_size,
                              hipStream_t stream) {
    const void* xin  = d_in[0];
    const void* h0   = d_in[1];
    const void* Wxh  = d_in[2];
    const void* Whh  = d_in[3];
    const void* bk   = d_in[4];
    const void* Wv   = d_in[5];
    const void* beta = d_in[6];

    char* ws = (char*)d_ws;
    int*   flag   = (int*)  (ws + 0);
    float* coeff  = (float*)(ws + 256);
    float* lsum   = (float*)(ws + 1024);      // 1280 f -> ends 6144
    float* ns_f32 = (float*)(ws + 8192);      // 256 KiB -> ends 270336
    float* eb     = (float*)(ws + 270336);    // 2.56 MB -> ends 2830336
    float* esv    = (float*)(ws + 2830336);   // 8.192 MB -> ends 11022336

    k_init <<<320, 256, 0, stream>>>(beta, flag, lsum, eb);
    k_state<<<256, 256, 0, stream>>>(flag, xin, h0, Wxh, Whh, ns_f32, d_out);
    k_bern <<<64, 64, 0, stream>>>(flag, ns_f32, bk, coeff);
    k_sv   <<<500, 256, 0, stream>>>(flag, ns_f32, Wv, d_out, esv);
    k_sum  <<<dim3(16, 64), 256, 0, stream>>>(esv, eb, coeff, lsum);
    k_write<<<dim3(16, 64), 256, 0, stream>>>(flag, esv, eb, coeff, lsum, d_out);
}

// Round 4
// 472.216 us; speedup vs baseline: 1.0524x; 1.0220x over previous
//
#include <hip/hip_runtime.h>
#include <cstdint>
#include <cstddef>

typedef unsigned int u32;
typedef unsigned short u16;

#define NB 64
#define DIN 512
#define UNITS 1024
#define TOPICS 20
#define VOCAB 32000
#define NS_OFF ((size_t)NB * TOPICS * VOCAB)

typedef __attribute__((ext_vector_type(8))) short s16x8;
typedef __attribute__((ext_vector_type(4))) float f32x4;

// ---------- bf16 helpers ----------
__device__ __forceinline__ float bf2f(u16 h) {
    union { u32 u; float f; } c; c.u = ((u32)h) << 16; return c.f;
}
__device__ __forceinline__ u16 f2bf(float f) {
    union { float f; u32 u; } c; c.f = f;
    u32 r = c.u + 0x7FFFu + ((c.u >> 16) & 1u);   // RNE
    return (u16)(r >> 16);
}
template<bool F32>
__device__ __forceinline__ float ldv(const void* p, size_t i) {
    if constexpr (F32) return ((const float*)p)[i];
    else return bf2f(((const u16*)p)[i]);
}
__device__ __forceinline__ float ldr(const void* p, size_t i, bool f32) {
    return f32 ? ((const float*)p)[i] : bf2f(((const u16*)p)[i]);
}

// ---------- threefry2x32-20, key (0,42), partitionable counts (0,i) ----------
__device__ __forceinline__ u32 threefry_bits_partitionable(u32 i) {
    const u32 ks0 = 0u, ks1 = 42u, ks2 = 0u ^ 42u ^ 0x1BD11BDAu;
    u32 x0 = 0u + ks0, x1 = i + ks1;
#define TF_R(r) { x0 += x1; x1 = (x1 << r) | (x1 >> (32 - r)); x1 ^= x0; }
    TF_R(13) TF_R(15) TF_R(26) TF_R(6)
    x0 += ks1; x1 += ks2 + 1u;
    TF_R(17) TF_R(29) TF_R(16) TF_R(24)
    x0 += ks2; x1 += ks0 + 2u;
    TF_R(13) TF_R(15) TF_R(26) TF_R(6)
    x0 += ks0; x1 += ks1 + 3u;
    TF_R(17) TF_R(29) TF_R(16) TF_R(24)
    x0 += ks1; x1 += ks2 + 4u;
    TF_R(13) TF_R(15) TF_R(26) TF_R(6)
    x0 += ks2; x1 += ks0 + 5u;
#undef TF_R
    return x0 ^ x1;
}

// ---------- init: self-detect dtype, eb = exp(beta), zero lsum, publish flag ----------
__global__ __launch_bounds__(256)
void k_init(const void* __restrict__ beta, int* __restrict__ flag,
            float* __restrict__ lsum, float* __restrict__ eb) {
    int tid = threadIdx.x, lane = tid & 63, w = tid >> 6;
    __shared__ int cnt_s[4];
    int cnt = 0;
    const u32* braw = (const u32*)beta;
    for (int i = tid; i < 1024; i += 256) {
        u32 x = braw[i];
        u32 e = (x >> 7) & 0xFFu;
        cnt += (e >= 110u && e <= 132u) ? 1 : 0;
    }
    for (int off = 32; off; off >>= 1) cnt += __shfl_down(cnt, off, 64);
    if (lane == 0) cnt_s[w] = cnt;
    __syncthreads();
    int total = cnt_s[0] + cnt_s[1] + cnt_s[2] + cnt_s[3];
    bool f32 = total < 512;

    size_t base = (size_t)blockIdx.x * 2000;
    for (int i = tid; i < 2000; i += 256)
        eb[base + i] = __expf(ldr(beta, base + i, f32));

    if (blockIdx.x == 0) {
        for (int i = tid; i < NB * TOPICS; i += 256) lsum[i] = 0.f;
        if (tid == 0) flag[0] = f32 ? 1 : 0;
    }
}

// ---------- A: next_state = x@Wxh + h@Whh ----------
template<bool F32>
__device__ void state_body(const void* xin, const void* h0, const void* Wxh,
                           const void* Whh, float* ns_f32, void* dout) {
    __shared__ float lx[DIN + UNITS];
    int b = blockIdx.x >> 2;
    int u = ((blockIdx.x & 3) << 8) | threadIdx.x;
    for (int i = threadIdx.x; i < DIN; i += 256)
        lx[i] = ldv<F32>(xin, (size_t)b * DIN + i);
    for (int i = threadIdx.x; i < UNITS; i += 256)
        lx[DIN + i] = ldv<F32>(h0, (size_t)b * UNITS + i);
    __syncthreads();
    float acc = 0.f;
#pragma unroll 8
    for (int k = 0; k < DIN; ++k)   acc += lx[k]       * ldv<F32>(Wxh, (size_t)k * UNITS + u);
#pragma unroll 8
    for (int k = 0; k < UNITS; ++k) acc += lx[DIN + k] * ldv<F32>(Whh, (size_t)k * UNITS + u);
    int idx = b * UNITS + u;
    ns_f32[idx] = acc;
    if constexpr (F32) ((float*)dout)[NS_OFF + idx] = acc;
    else               ((u16*)dout)[NS_OFF + idx]   = f2bf(acc);
}
__global__ __launch_bounds__(256)
void k_state(const int* __restrict__ flag, const void* xin, const void* h0,
             const void* Wxh, const void* Whh,
             float* __restrict__ ns_f32, void* dout) {
    if (*flag) state_body<true>(xin, h0, Wxh, Whh, ns_f32, dout);
    else       state_body<false>(xin, h0, Wxh, Whh, ns_f32, dout);
}

// ---------- B: coeff_b = 1 - bernoulli_sample ----------
template<bool F32>
__device__ void bern_body(const float* ns, const void* bk, float* coeff) {
    int b = blockIdx.x, lane = threadIdx.x;
    float s = 0.f;
#pragma unroll
    for (int i = 0; i < UNITS / 64; ++i) {
        int k = lane + (i << 6);
        s += ns[b * UNITS + k] * ldv<F32>(bk, k);
    }
    for (int off = 32; off; off >>= 1) s += __shfl_down(s, off, 64);
    if (lane == 0) {
        float sp = log1pf(expf(s));              // softplus
        float p  = 1.f / (1.f + expf(-sp));      // sigmoid
        u32 bits = threefry_bits_partitionable((u32)b);
        union { u32 u; float f; } c; c.u = (bits >> 9) | 0x3f800000u;
        float uni = c.f - 1.0f;
        coeff[b] = (uni < p) ? 0.f : 1.f;        // (1 - sample)
    }
}
__global__ __launch_bounds__(64)
void k_bern(const int* __restrict__ flag, const float* __restrict__ ns,
            const void* bk, float* __restrict__ coeff) {
    if (*flag) bern_body<true>(ns, bk, coeff);
    else       bern_body<false>(ns, bk, coeff);
}

// ============================================================================
// C: esv[b][v] = exp( ns[b][:] @ Wv[:,v] )
//
// bf16 path (the benched one): MFMA 16x16x32_bf16, grid 500 x 256 (4 waves),
// block v-tile 64, wave wn owns cols wn*16..+15, all 64 b-rows.
// K = 1024 in 16 tiles of 64. Per tile per thread: exactly 4 global_load_lds
// (2 A + 2 B, 16B each) -> 4-buffer LDS (64KB), 3 stages in flight,
// raw s_barrier + counted "s_waitcnt vmcnt(8)" (never 0 in the loop;
// __syncthreads would force a vmcnt(0) drain and kill the pipeline).
//   A: [row b][8 chunks of 8 bf16], chunk slot XOR-swizzled with (row&7)
//      via PRE-SWIZZLED GLOBAL SOURCE (linear LDS dest required by DMA);
//      frag read = ds_read_b128, conflict-free.
//   B: linear [k][64 v] (DMA order); frag read = 8 x ds_read_u16 (k-strided,
//      ~4-way, LDS port not critical). Chosen over ds_read_b64_tr_b16 to
//      bound correctness risk this round.
// f32 path: session-verified VALU tile, shares the same hoisted smem.
// ============================================================================
#define PAD 68
#define SV_STAGE_B 16384                 // bytes per stage: A 8KB + B 8KB
#define SV_SMEM_BYTES (4 * SV_STAGE_B)   // 64KB (mfma) >= 34816 (f32 path)

__device__ __forceinline__ void gld16(const void* g, void* l) {
    __builtin_amdgcn_global_load_lds(
        (const __attribute__((address_space(1))) void*)g,
        (__attribute__((address_space(3))) void*)l, 16, 0, 0);
}

// stage tile t into buffer buf: per thread 4 x global_load_lds(16B)
__device__ __forceinline__ void sv_stage(const short* __restrict__ ns16,
                                         const short* __restrict__ Wv,
                                         char* smem, int buf, int t, int v0,
                                         int wn, int lane) {
    char* sb = smem + buf * SV_STAGE_B;
#pragma unroll
    for (int r = 0; r < 2; ++r) {
        int ib = r * 256 + wn * 64;          // wave-uniform LDS base index
        int i  = ib + lane;
        // A: row = i>>3, chunk slot i&7 holds global chunk (i&7)^((i>>3)&7)
        const short* gA = ns16 + (size_t)(i >> 3) * UNITS + t * 64
                        + (((i & 7) ^ ((i >> 3) & 7)) << 3);
        gld16(gA, sb + (size_t)ib * 16);
        // B: linear [k][64v]; k = i>>3, v-chunk = i&7
        const short* gB = Wv + (size_t)(t * 64 + (i >> 3)) * VOCAB + v0 + ((i & 7) << 3);
        gld16(gB, sb + 8192 + (size_t)ib * 16);
    }
}

__device__ __forceinline__ void sv_compute(const char* smem, int buf,
                                           int lane, int wn, f32x4 acc[4]) {
    const char*  sb = smem + buf * SV_STAGE_B;
    const short* Bs = (const short*)(sb + 8192);
#pragma unroll
    for (int kk = 0; kk < 2; ++kk) {
        // B frag: lane holds B[kk*32 + (lane>>4)*8 + e][wn*16 + (lane&15)]
        s16x8 bf;
#pragma unroll
        for (int e = 0; e < 8; ++e)
            bf[e] = Bs[(kk * 32 + ((lane >> 4) << 3) + e) * 64 + wn * 16 + (lane & 15)];
#pragma unroll
        for (int mf = 0; mf < 4; ++mf) {
            int row  = mf * 16 + (lane & 15);
            int slot = (kk * 4 + (lane >> 4)) ^ (row & 7);
            s16x8 af = *(const s16x8*)(sb + row * 128 + slot * 16);
            acc[mf] = __builtin_amdgcn_mfma_f32_16x16x32_bf16(af, bf, acc[mf], 0, 0, 0);
        }
    }
}

__device__ void sv_mfma_body(const short* __restrict__ ns16,
                             const short* __restrict__ Wv,
                             float* __restrict__ esv, char* smem) {
    const int tid  = threadIdx.x;
    const int lane = tid & 63;
    const int wn   = tid >> 6;
    const int v0   = blockIdx.x * 64;

    f32x4 acc[4];
#pragma unroll
    for (int m = 0; m < 4; ++m) acc[m] = (f32x4){0.f, 0.f, 0.f, 0.f};

    // prologue: 3 stages in flight
    sv_stage(ns16, Wv, smem, 0, 0, v0, wn, lane);
    sv_stage(ns16, Wv, smem, 1, 1, v0, wn, lane);
    sv_stage(ns16, Wv, smem, 2, 2, v0, wn, lane);

    // steady state: before STEP(T) wait, stages {T, T+1, T+2} are outstanding
    // (4 loads each) -> vmcnt(8) drains exactly stage T. Tail: 4 / 0.
#define SV_STEP(T, VM)                                                        \
    asm volatile("s_waitcnt vmcnt(" #VM ")" ::: "memory");                    \
    __builtin_amdgcn_s_barrier();                                             \
    sv_compute(smem, (T) & 3, lane, wn, acc);                                 \
    __builtin_amdgcn_s_barrier();                                             \
    asm volatile("" ::: "memory");                                            \
    if ((T) + 3 < 16)                                                         \
        sv_stage(ns16, Wv, smem, ((T) + 3) & 3, (T) + 3, v0, wn, lane);

    SV_STEP(0, 8)  SV_STEP(1, 8)  SV_STEP(2, 8)  SV_STEP(3, 8)
    SV_STEP(4, 8)  SV_STEP(5, 8)  SV_STEP(6, 8)  SV_STEP(7, 8)
    SV_STEP(8, 8)  SV_STEP(9, 8)  SV_STEP(10, 8) SV_STEP(11, 8)
    SV_STEP(12, 8) SV_STEP(13, 8) SV_STEP(14, 4) SV_STEP(15, 0)
#undef SV_STEP

    // C/D layout: row=(lane>>4)*4+reg, col=lane&15  [m89-verified]
    const int col = v0 + wn * 16 + (lane & 15);
#pragma unroll
    for (int mf = 0; mf < 4; ++mf)
#pragma unroll
        for (int r = 0; r < 4; ++r) {
            int b = mf * 16 + (lane >> 4) * 4 + r;
            esv[(size_t)b * VOCAB + col] = __expf(acc[mf][r]);
        }
}

__device__ void sv_f32_body(const float* __restrict__ ns, const float* __restrict__ Wv,
                            float* __restrict__ esv, float* As, float* Bs) {
    int tid = threadIdx.x;
    int vt = tid & 7;           // 8 v-threads x 8 v = 64 v
    int bg = tid >> 3;          // 32 groups x 2 b = 64 b
    int v0 = blockIdx.x * 64;
    float acc[2][8];
#pragma unroll
    for (int r = 0; r < 2; ++r)
#pragma unroll
        for (int j = 0; j < 8; ++j) acc[r][j] = 0.f;

    for (int k0 = 0; k0 < UNITS; k0 += 64) {
        __syncthreads();
        for (int e = tid; e < 1024; e += 256) {      // stage A: ns[64b][64k]
            int row = e >> 4, c4 = e & 15;
            *(float4*)&As[row * PAD + c4 * 4] =
                *(const float4*)&ns[row * UNITS + k0 + c4 * 4];
        }
        for (int e = tid; e < 1024; e += 256) {      // stage B: Wv[64k][64v]
            int row = e >> 4, c4 = e & 15;
            *(float4*)&Bs[row * PAD + c4 * 4] =
                *(const float4*)(Wv + (size_t)(k0 + row) * VOCAB + v0 + c4 * 4);
        }
        __syncthreads();
#pragma unroll 4
        for (int u = 0; u < 64; u += 4) {
            float4 a0 = *(float4*)&As[(bg * 2 + 0) * PAD + u];
            float4 a1 = *(float4*)&As[(bg * 2 + 1) * PAD + u];
            float aa0[4] = {a0.x, a0.y, a0.z, a0.w};
            float aa1[4] = {a1.x, a1.y, a1.z, a1.w};
#pragma unroll
            for (int uu = 0; uu < 4; ++uu) {
                float4 b0 = *(float4*)&Bs[(u + uu) * PAD + vt * 8];
                float4 b1 = *(float4*)&Bs[(u + uu) * PAD + vt * 8 + 4];
                float bb[8] = {b0.x, b0.y, b0.z, b0.w, b1.x, b1.y, b1.z, b1.w};
#pragma unroll
                for (int j = 0; j < 8; ++j) {
                    acc[0][j] = fmaf(aa0[uu], bb[j], acc[0][j]);
                    acc[1][j] = fmaf(aa1[uu], bb[j], acc[1][j]);
                }
            }
        }
    }
#pragma unroll
    for (int r = 0; r < 2; ++r) {
        float4 e0, e1;
        e0.x = __expf(acc[r][0]); e0.y = __expf(acc[r][1]);
        e0.z = __expf(acc[r][2]); e0.w = __expf(acc[r][3]);
        e1.x = __expf(acc[r][4]); e1.y = __expf(acc[r][5]);
        e1.z = __expf(acc[r][6]); e1.w = __expf(acc[r][7]);
        float* dst = esv + (size_t)(bg * 2 + r) * VOCAB + v0 + vt * 8;
        *(float4*)dst = e0;
        *(float4*)(dst + 4) = e1;
    }
}

__global__ __launch_bounds__(256)
void k_sv(const int* __restrict__ flag, const float* __restrict__ ns,
          const void* Wv, const void* dout, float* __restrict__ esv) {
    __shared__ __align__(16) char smem[SV_SMEM_BYTES];
    if (*flag) {
        float* As = (float*)smem;
        sv_f32_body(ns, (const float*)Wv, esv, As, As + 64 * PAD);
    } else {
        sv_mfma_body((const short*)dout + NS_OFF, (const short*)Wv, esv, smem);
    }
}

// ---------- D1: lsum[b][t] = sum_v esv[b][v] * (c ? eb[t][v] : 1) ----------
__global__ __launch_bounds__(256)
void k_sum(const float* __restrict__ esv, const float* __restrict__ eb,
           const float* __restrict__ coeff, float* __restrict__ lsum) {
    int b = blockIdx.y, tid = threadIdx.x;
    float c = coeff[b];
    const float4* e4 = (const float4*)(esv + (size_t)b * VOCAB);
    int i0 = blockIdx.x * 256 + tid;
    __shared__ float red[4][TOPICS];
    int lane = tid & 63, w = tid >> 6;

    if (c != 0.f) {
        float acc[TOPICS];
#pragma unroll
        for (int t = 0; t < TOPICS; ++t) acc[t] = 0.f;
        for (int i = i0; i < VOCAB / 4; i += 4096) {
            float4 e = e4[i];
#pragma unroll
            for (int t = 0; t < TOPICS; ++t) {
                float4 g = *(const float4*)(eb + (size_t)t * VOCAB + i * 4);
                acc[t] += e.x * g.x + e.y * g.y + e.z * g.z + e.w * g.w;
            }
        }
#pragma unroll
        for (int t = 0; t < TOPICS; ++t) {
            float v = acc[t];
            for (int off = 32; off; off >>= 1) v += __shfl_down(v, off, 64);
            if (lane == 0) red[w][t] = v;
        }
        __syncthreads();
        if (tid < TOPICS) {
            float s = red[0][tid] + red[1][tid] + red[2][tid] + red[3][tid];
            atomicAdd(&lsum[b * TOPICS + tid], s);
        }
    } else {
        float a = 0.f;
        for (int i = i0; i < VOCAB / 4; i += 4096) {
            float4 e = e4[i];
            a += e.x + e.y + e.z + e.w;
        }
        for (int off = 32; off; off >>= 1) a += __shfl_down(a, off, 64);
        if (lane == 0) red[w][0] = a;
        __syncthreads();
        if (tid < TOPICS) {
            float s = red[0][0] + red[1][0] + red[2][0] + red[3][0];
            atomicAdd(&lsum[b * TOPICS + tid], s);
        }
    }
}

// ---------- D2: out[b][t][v] = esv[b][v] * (c ? eb[t][v] : 1) / lsum[b][t] ----------
template<bool F32>
__device__ void write_body(const float* esv, const float* eb, const float* coeff,
                           const float* lsum, void* dout) {
    int b = blockIdx.y, tid = threadIdx.x;
    int v0 = blockIdx.x * 2048 + tid * 8;
    if (v0 >= VOCAB) return;
    float c = coeff[b];
    const float* er = esv + (size_t)b * VOCAB + v0;
    float4 e0 = *(const float4*)er;
    float4 e1 = *(const float4*)(er + 4);
#pragma unroll 4
    for (int t = 0; t < TOPICS; ++t) {
        float inv = 1.0f / lsum[b * TOPICS + t];
        float o0, o1, o2, o3, o4, o5, o6, o7;
        if (c != 0.f) {
            const float* gr = eb + (size_t)t * VOCAB + v0;
            float4 g0 = *(const float4*)gr;
            float4 g1 = *(const float4*)(gr + 4);
            o0 = e0.x * g0.x * inv; o1 = e0.y * g0.y * inv;
            o2 = e0.z * g0.z * inv; o3 = e0.w * g0.w * inv;
            o4 = e1.x * g1.x * inv; o5 = e1.y * g1.y * inv;
            o6 = e1.z * g1.z * inv; o7 = e1.w * g1.w * inv;
        } else {
            o0 = e0.x * inv; o1 = e0.y * inv; o2 = e0.z * inv; o3 = e0.w * inv;
            o4 = e1.x * inv; o5 = e1.y * inv; o6 = e1.z * inv; o7 = e1.w * inv;
        }
        size_t off = (size_t)b * TOPICS * VOCAB + (size_t)t * VOCAB + v0;
        if constexpr (F32) {
            float4 s0 = {o0, o1, o2, o3}, s1 = {o4, o5, o6, o7};
            *(float4*)((float*)dout + off) = s0;
            *(float4*)((float*)dout + off + 4) = s1;
        } else {
            uint4 st;
            st.x = (u32)f2bf(o0) | ((u32)f2bf(o1) << 16);
            st.y = (u32)f2bf(o2) | ((u32)f2bf(o3) << 16);
            st.z = (u32)f2bf(o4) | ((u32)f2bf(o5) << 16);
            st.w = (u32)f2bf(o6) | ((u32)f2bf(o7) << 16);
            *(uint4*)((u16*)dout + off) = st;
        }
    }
}
__global__ __launch_bounds__(256)
void k_write(const int* __restrict__ flag, const float* __restrict__ esv,
             const float* __restrict__ eb, const float* __restrict__ coeff,
             const float* __restrict__ lsum, void* dout) {
    if (*flag) write_body<true>(esv, eb, coeff, lsum, dout);
    else       write_body<false>(esv, eb, coeff, lsum, dout);
}

extern "C" void kernel_launch(void* const* d_in, const int* in_sizes, int n_in,
                              void* d_out, int out_size, void* d_ws, size_t ws_size,
                              hipStream_t stream) {
    const void* xin  = d_in[0];
    const void* h0   = d_in[1];
    const void* Wxh  = d_in[2];
    const void* Whh  = d_in[3];
    const void* bk   = d_in[4];
    const void* Wv   = d_in[5];
    const void* beta = d_in[6];

    char* ws = (char*)d_ws;
    int*   flag   = (int*)  (ws + 0);
    float* coeff  = (float*)(ws + 256);
    float* lsum   = (float*)(ws + 1024);      // 1280 f -> ends 6144
    float* ns_f32 = (float*)(ws + 8192);      // 256 KiB -> ends 270336
    float* eb     = (float*)(ws + 270336);    // 2.56 MB -> ends 2830336
    float* esv    = (float*)(ws + 2830336);   // 8.192 MB -> ends 11022336

    k_init <<<320, 256, 0, stream>>>(beta, flag, lsum, eb);
    k_state<<<256, 256, 0, stream>>>(flag, xin, h0, Wxh, Whh, ns_f32, d_out);
    k_bern <<<64, 64, 0, stream>>>(flag, ns_f32, bk, coeff);
    k_sv   <<<500, 256, 0, stream>>>(flag, ns_f32, Wv, d_out, esv);
    k_sum  <<<dim3(16, 64), 256, 0, stream>>>(esv, eb, coeff, lsum);
    k_write<<<dim3(16, 64), 256, 0, stream>>>(flag, esv, eb, coeff, lsum, d_out);
}